// Round 4
// baseline (169.103 us; speedup 1.0000x reference)
//
#include <hip/hip_runtime.h>

// BiAlignLayer collapses algebraically:
//   softmax rows/cols sum to 1  =>  mean over seq of weighted_i / weighted_j
//   equal mean(i) / mean(j) exactly.  With u = mean_l(i) - mean_m(j):
//   out = 0.5 * ( relu(u@W + b) + relu(-u@W + b) )
// Stage 1: streaming reduce over L (~128 MB mandatory read).
//   R4: nt loads 3.0 -> 4.2 TB/s (L1 miss-queue bypass). R5: 16-deep bursts.
//   R6 (block shape), R7 (stream split): NEUTRAL -- structure exhausted.
//   R8 probe: re-read of block's chunk was L2-hot (+0.8 us = pure issue cost)
//   -> latency/issue proven non-limiting; stage1 ~28 us @ ~4.6 TB/s remains
//   the only accounting consistent with 3x40.5 us fills + ~4 us stage2.
//   R9 (this round): __builtin_nontemporal_load sets the nt (no-allocate/
//   stream) policy at L2 AND the memory-side Infinity Cache, which can cost
//   DRAM burst/row efficiency (4.6/6.6 = 0.70). gfx950 separates SCOPE
//   (sc0/sc1: L1 bypass) from TEMPORAL policy (nt). This round: inline-asm
//   global_load_dwordx4 ... sc0  == L1 bypass (R4's active ingredient) with
//   NORMAL temporal policy at L2/L3. Manual vmcnt fence + sched_barrier(0)
//   (rule #18: compiler doesn't track inline-asm loads) + reg keep-alives.
// Stage 2: [B,D] x [D,NN] matvec + bias + dual relu (folds 32+32 partials)

#define BB 32
#define LL 1024
#define DD 512
#define NNN 512
#define SPLIT 32
#define ROWS (LL / SPLIT)          // 32 rows per chunk = 64 KiB
#define NVEC (ROWS * DD / 4)       // 4096 float4 per chunk
#define T1 256                     // stage1 block size (4 waves)
#define NWIN (NVEC / T1)           // 16 windows -> 16-deep bursts

typedef float f4 __attribute__((ext_vector_type(4)));

__global__ __launch_bounds__(T1, 4) void bialign_stage1(
    const float* __restrict__ gi, const float* __restrict__ gj,
    float* __restrict__ part) {
    const int blk = blockIdx.x;            // [0, 2*BB*SPLIT)
    const int sel = blk >> 10;             // 0: i-stream, 1: j-stream
    const int idx = blk & 1023;            // b*SPLIT + s
    const int b = idx >> 5;
    const int s = idx & (SPLIT - 1);
    const float* src = sel ? gj : gi;
    const size_t base = (size_t)b * LL * DD + (size_t)s * ROWS * DD;
    const f4* p4 = (const f4*)(src + base) + threadIdx.x;
    const int t = threadIdx.x;

    // 16 independent loads in flight: sc0 = device-scope (L1 bypass),
    // temporal at L2/L3. 64 data VGPRs + 32 addr VGPRs < 128-VGPR cap.
    f4 a[NWIN];
    #pragma unroll
    for (int w = 0; w < NWIN; ++w) {
        asm volatile("global_load_dwordx4 %0, %1, off sc0"
                     : "=v"(a[w])
                     : "v"(p4 + (size_t)w * T1)
                     : "memory");
    }
    // Compiler does not track inline-asm loads in its vmcnt model: fence
    // manually, then pin the schedule (nothing may hoist above this), then
    // route every loaded reg through a volatile no-op so all consumers see
    // the post-fence value.
    asm volatile("s_waitcnt vmcnt(0)" ::: "memory");
    __builtin_amdgcn_sched_barrier(0);
    #pragma unroll
    for (int w = 0; w < NWIN; ++w) {
        asm volatile("" : "+v"(a[w]));
    }

    f4 acc0 = a[0], acc1 = a[1], acc2 = a[2], acc3 = a[3];
    #pragma unroll
    for (int w = 4; w < NWIN; w += 4) {
        acc0 += a[w + 0];
        acc1 += a[w + 1];
        acc2 += a[w + 2];
        acc3 += a[w + 3];
    }
    acc0 += acc1;
    acc2 += acc3;
    acc0 += acc2;

    // Window stride = 256 f4 = 1024 floats == 0 mod 512 -> each thread's
    // d-phase is constant: phase(t) = (4t) mod 512; 2 phase-groups (t>>7).
    __shared__ float sm[2 * DD];
    f4* sm4 = (f4*)sm;
    sm4[(t >> 7) * 128 + (t & 127)] = acc0;     // group g, slot p = t&127
    __syncthreads();
    if (t < 128) {
        f4 s0 = sm4[t] + sm4[128 + t];
        ((f4*)(part + (size_t)blk * DD))[t] = s0;  // [2][B*SPLIT][D] layout
    }
}

// Stage 2: grid (B, 4) blocks of 256. Block (b, ns) computes out[b, ns*128 .. +127].
// u[d] = (sum_i_partials - sum_j_partials) / L, then threads t<128 accumulate
// d=[0,256) for col ns*128+t; t>=128 accumulate d=[256,512); combine in LDS.
__global__ __launch_bounds__(256) void bialign_stage2(
    const float* __restrict__ part, const float* __restrict__ W,
    const float* __restrict__ bias, float* __restrict__ out) {
    const int b = blockIdx.x;
    const int ns = blockIdx.y;
    const int t = threadIdx.x;              // 256

    __shared__ float u[DD];
    __shared__ float psum[256];
    for (int d = t; d < DD; d += 256) {
        const float* pi = part + (size_t)b * SPLIT * DD + d;
        const float* pj = pi + (size_t)BB * SPLIT * DD;
        float sum = 0.f;
        #pragma unroll
        for (int k = 0; k < SPLIT; ++k) sum += pi[(size_t)k * DD];
        #pragma unroll
        for (int k = 0; k < SPLIT; ++k) sum -= pj[(size_t)k * DD];
        u[d] = sum * (1.0f / (float)LL);
    }
    __syncthreads();

    const int col = ns * 128 + (t & 127);
    const int d0 = (t >> 7) * 256;          // 0 or 256
    float acc = 0.f;
    #pragma unroll 8
    for (int d = 0; d < 256; ++d) {
        acc = fmaf(u[d0 + d], W[(size_t)(d0 + d) * NNN + col], acc);
    }
    psum[t] = acc;
    __syncthreads();
    if (t < 128) {
        const float dot = psum[t] + psum[t + 128];
        const float bb = bias[col];
        const float r = 0.5f * (fmaxf(dot + bb, 0.f) + fmaxf(bb - dot, 0.f));
        out[(size_t)b * NNN + col] = r;
    }
}

extern "C" void kernel_launch(void* const* d_in, const int* in_sizes, int n_in,
                              void* d_out, int out_size, void* d_ws, size_t ws_size,
                              hipStream_t stream) {
    const float* gi   = (const float*)d_in[0];   // [B, L, D]
    const float* gj   = (const float*)d_in[1];   // [B, L, D]
    const float* W    = (const float*)d_in[2];   // [D, NN]
    const float* bias = (const float*)d_in[3];   // [NN]
    float* out = (float*)d_out;                  // [B, NN]
    float* part = (float*)d_ws;                  // 2*B*SPLIT*D floats = 4 MB

    bialign_stage1<<<2 * BB * SPLIT, T1, 0, stream>>>(gi, gj, part);
    bialign_stage2<<<dim3(BB, 4), 256, 0, stream>>>(part, W, bias, out);
}

// Round 5
// 157.632 us; speedup vs baseline: 1.0728x; 1.0728x over previous
//
#include <hip/hip_runtime.h>

// BiAlignLayer collapses algebraically:
//   softmax rows/cols sum to 1  =>  mean over seq of weighted_i / weighted_j
//   equal mean(i) / mean(j) exactly.  With u = mean_l(i) - mean_m(j):
//   out = 0.5 * ( relu(u@W + b) + relu(-u@W + b) )
// Stage 1: streaming reduce over L (~128 MB mandatory read).
//   Read-path ladder (measured): normal loads 3.0 TB/s; sc0 2.9 TB/s
//   (R9: L1-allocating wall is policy-independent; FETCH=67MB proved L3
//   retains half the input yet the path still throttles -> wall is in the
//   CU->L2 request path, upstream of data residency); nt 4.6 TB/s.
//   R6 (block shape), R7 (stream split), R8 (depth/latency): all neutral.
//   R10 (this round): the one untried mechanism -- global_load_lds DMA.
//   Data returns L2 -> LDS directly, skipping the L1/VGPR return machinery
//   where the 4.6 TB/s wall presumably lives. aux=2 keeps the nt (stream/
//   no-allocate) DRAM-friendly policy. 64 KiB chunk staged through 32 KB
//   LDS in two 8-window batches; each wave consumes only its own DMA
//   slices (no cross-wave barrier); 8 x 4 KB in flight per block,
//   4 blocks/CU (LDS 36 KB) = 128 KB in flight per CU.
// Stage 2: [B,D] x [D,NN] matvec + bias + dual relu (folds 32+32 partials)

#define BB 32
#define LL 1024
#define DD 512
#define NNN 512
#define SPLIT 32
#define ROWS (LL / SPLIT)          // 32 rows per chunk = 64 KiB
#define NVEC (ROWS * DD / 4)       // 4096 f4 per chunk
#define T1 256                     // stage1 block size (4 waves)
#define NBATCH 8                   // windows per batch (4 KB each)

typedef float f4 __attribute__((ext_vector_type(4)));

__global__ __launch_bounds__(T1, 4) void bialign_stage1(
    const float* __restrict__ gi, const float* __restrict__ gj,
    float* __restrict__ part) {
    const int blk = blockIdx.x;            // [0, 2*BB*SPLIT)
    const int sel = blk >> 10;             // 0: i-stream, 1: j-stream
    const int idx = blk & 1023;            // b*SPLIT + s
    const int b = idx >> 5;
    const int s = idx & (SPLIT - 1);
    const float* src = sel ? gj : gi;
    const size_t base = (size_t)b * LL * DD + (size_t)s * ROWS * DD;
    const int t = threadIdx.x;
    const int wv = t >> 6;                 // wave id 0..3

    __shared__ f4 stage[NBATCH * 256];     // 32 KB staging (8 windows)
    __shared__ float sm[2 * DD];           // 4 KB reduce buffer

    // Per-lane global address; DMA LDS dest = wave-uniform base + lane*16.
    // Window w, wave wv: LDS f4-slot w*256 + wv*64 (+ lane), matching
    // global f4-index w*256 + t. Thread t later reads slots k*256 + t,
    // i.e. only LDS its own wave's DMA wrote -> vmcnt fence suffices.
    const f4* g = (const f4*)(src + base) + t;

    // ---- batch 1: windows 0..7 ----
    #pragma unroll
    for (int w = 0; w < NBATCH; ++w) {
        __builtin_amdgcn_global_load_lds(g + (size_t)w * 256,
                                         (f4*)stage + w * 256 + wv * 64,
                                         16, 0, 2 /* nt */);
    }
    asm volatile("s_waitcnt vmcnt(0)" ::: "memory");
    __builtin_amdgcn_sched_barrier(0);

    f4 acc0 = stage[0 * 256 + t], acc1 = stage[1 * 256 + t];
    f4 acc2 = stage[2 * 256 + t], acc3 = stage[3 * 256 + t];
    acc0 += stage[4 * 256 + t];
    acc1 += stage[5 * 256 + t];
    acc2 += stage[6 * 256 + t];
    acc3 += stage[7 * 256 + t];

    // All batch-1 ds_reads must have landed before DMA overwrites LDS.
    asm volatile("s_waitcnt lgkmcnt(0)" ::: "memory");
    __builtin_amdgcn_sched_barrier(0);

    // ---- batch 2: windows 8..15 into the same slots ----
    #pragma unroll
    for (int w = 0; w < NBATCH; ++w) {
        __builtin_amdgcn_global_load_lds(g + (size_t)(NBATCH + w) * 256,
                                         (f4*)stage + w * 256 + wv * 64,
                                         16, 0, 2 /* nt */);
    }
    asm volatile("s_waitcnt vmcnt(0)" ::: "memory");
    __builtin_amdgcn_sched_barrier(0);

    acc0 += stage[0 * 256 + t];
    acc1 += stage[1 * 256 + t];
    acc2 += stage[2 * 256 + t];
    acc3 += stage[3 * 256 + t];
    acc0 += stage[4 * 256 + t];
    acc1 += stage[5 * 256 + t];
    acc2 += stage[6 * 256 + t];
    acc3 += stage[7 * 256 + t];
    acc0 += acc1;
    acc2 += acc3;
    acc0 += acc2;

    // Window stride = 256 f4 = 1024 floats == 0 mod 512 -> each thread's
    // d-phase is constant: phase(t) = (4t) mod 512; 2 phase-groups (t>>7).
    f4* sm4 = (f4*)sm;
    sm4[(t >> 7) * 128 + (t & 127)] = acc0;     // group g, slot p = t&127
    __syncthreads();
    if (t < 128) {
        f4 s0 = sm4[t] + sm4[128 + t];
        ((f4*)(part + (size_t)blk * DD))[t] = s0;  // [2][B*SPLIT][D] layout
    }
}

// Stage 2: grid (B, 4) blocks of 256. Block (b, ns) computes out[b, ns*128 .. +127].
// u[d] = (sum_i_partials - sum_j_partials) / L, then threads t<128 accumulate
// d=[0,256) for col ns*128+t; t>=128 accumulate d=[256,512); combine in LDS.
__global__ __launch_bounds__(256) void bialign_stage2(
    const float* __restrict__ part, const float* __restrict__ W,
    const float* __restrict__ bias, float* __restrict__ out) {
    const int b = blockIdx.x;
    const int ns = blockIdx.y;
    const int t = threadIdx.x;              // 256

    __shared__ float u[DD];
    __shared__ float psum[256];
    for (int d = t; d < DD; d += 256) {
        const float* pi = part + (size_t)b * SPLIT * DD + d;
        const float* pj = pi + (size_t)BB * SPLIT * DD;
        float sum = 0.f;
        #pragma unroll
        for (int k = 0; k < SPLIT; ++k) sum += pi[(size_t)k * DD];
        #pragma unroll
        for (int k = 0; k < SPLIT; ++k) sum -= pj[(size_t)k * DD];
        u[d] = sum * (1.0f / (float)LL);
    }
    __syncthreads();

    const int col = ns * 128 + (t & 127);
    const int d0 = (t >> 7) * 256;          // 0 or 256
    float acc = 0.f;
    #pragma unroll 8
    for (int d = 0; d < 256; ++d) {
        acc = fmaf(u[d0 + d], W[(size_t)(d0 + d) * NNN + col], acc);
    }
    psum[t] = acc;
    __syncthreads();
    if (t < 128) {
        const float dot = psum[t] + psum[t + 128];
        const float bb = bias[col];
        const float r = 0.5f * (fmaxf(dot + bb, 0.f) + fmaxf(bb - dot, 0.f));
        out[(size_t)b * NNN + col] = r;
    }
}

extern "C" void kernel_launch(void* const* d_in, const int* in_sizes, int n_in,
                              void* d_out, int out_size, void* d_ws, size_t ws_size,
                              hipStream_t stream) {
    const float* gi   = (const float*)d_in[0];   // [B, L, D]
    const float* gj   = (const float*)d_in[1];   // [B, L, D]
    const float* W    = (const float*)d_in[2];   // [D, NN]
    const float* bias = (const float*)d_in[3];   // [NN]
    float* out = (float*)d_out;                  // [B, NN]
    float* part = (float*)d_ws;                  // 2*B*SPLIT*D floats = 4 MB

    bialign_stage1<<<2 * BB * SPLIT, T1, 0, stream>>>(gi, gj, part);
    bialign_stage2<<<dim3(BB, 4), 256, 0, stream>>>(part, W, bias, out);
}